// Round 13
// baseline (182.388 us; speedup 1.0000x reference)
//
#include <hip/hip_runtime.h>
#include <math.h>

// Problem constants (fixed by setup_inputs)
#define D 1024
#define B 32
#define N 1024          // patches per image (32x32)
#define SIDE 32
#define OUT 512
#define NLAYER 4
#define TAU_INV (1.0f/0.07f)
#define EPS_NORM 1e-12f

typedef float f32x4 __attribute__((ext_vector_type(4)));

__device__ __forceinline__ float wave_sum(float s) {
#pragma unroll
    for (int m = 32; m; m >>= 1) s += __shfl_xor(s, m);
    return s;
}

// ---------------------------------------------------------------------------
// Kernel 1: cls logits (blocks 0..31) + combined seg-weight prep (block 32).
//   what[l][:] = (w0/||w0|| - w1/||w1||) / tau    (seg logit-diff = x.what/||x||)
// ---------------------------------------------------------------------------
__global__ void cls_prep_kernel(const float* c0, const float* wc0,
                                const float* c1, const float* wc1,
                                const float* c2, const float* wc2,
                                const float* c3, const float* wc3,
                                const float* s0, const float* s1,
                                const float* s2, const float* s3,
                                float* out, float* what) {
    if (blockIdx.x == 32) {
        // prep: wave l handles layer l
        int l = threadIdx.x >> 6;
        int lane = threadIdx.x & 63;
        const float* w = (l == 0) ? s0 : (l == 1) ? s1 : (l == 2) ? s2 : s3;
        float4 wa[4], wb[4];
        float q00 = 0.f, q11 = 0.f;
#pragma unroll
        for (int kk = 0; kk < 4; ++kk) {
            int off = kk * 256 + lane * 4;
            wa[kk] = *reinterpret_cast<const float4*>(w + off);
            wb[kk] = *reinterpret_cast<const float4*>(w + D + off);
            q00 += wa[kk].x * wa[kk].x + wa[kk].y * wa[kk].y + wa[kk].z * wa[kk].z + wa[kk].w * wa[kk].w;
            q11 += wb[kk].x * wb[kk].x + wb[kk].y * wb[kk].y + wb[kk].z * wb[kk].z + wb[kk].w * wb[kk].w;
        }
        q00 = wave_sum(q00); q11 = wave_sum(q11);
        float iw0 = TAU_INV / fmaxf(sqrtf(q00), EPS_NORM);
        float iw1 = TAU_INV / fmaxf(sqrtf(q11), EPS_NORM);
        float* o = what + (size_t)l * D;
#pragma unroll
        for (int kk = 0; kk < 4; ++kk) {
            int off = kk * 256 + lane * 4;
            float4 r;
            r.x = wa[kk].x * iw0 - wb[kk].x * iw1;
            r.y = wa[kk].y * iw0 - wb[kk].y * iw1;
            r.z = wa[kk].z * iw0 - wb[kk].z * iw1;
            r.w = wa[kk].w * iw0 - wb[kk].w * iw1;
            *reinterpret_cast<float4*>(o + off) = r;
        }
        return;
    }

    int wid = blockIdx.x * 4 + (threadIdx.x >> 6);   // 0..127
    int lane = threadIdx.x & 63;
    int l = wid >> 5;
    int b = wid & 31;
    const float* cls; const float* wc;
    if      (l == 0) { cls = c0; wc = wc0; }
    else if (l == 1) { cls = c1; wc = wc1; }
    else if (l == 2) { cls = c2; wc = wc2; }
    else             { cls = c3; wc = wc3; }
    const float* x = cls + (size_t)b * D;

    float sxx = 0.f, sx0 = 0.f, sx1 = 0.f, q00 = 0.f, q11 = 0.f;
#pragma unroll
    for (int kk = 0; kk < 4; ++kk) {
        int off = kk * 256 + lane * 4;
        const float4 v  = *reinterpret_cast<const float4*>(x + off);
        const float4 a  = *reinterpret_cast<const float4*>(wc + off);
        const float4 bb = *reinterpret_cast<const float4*>(wc + D + off);
        sxx += v.x * v.x + v.y * v.y + v.z * v.z + v.w * v.w;
        sx0 += v.x * a.x + v.y * a.y + v.z * a.z + v.w * a.w;
        sx1 += v.x * bb.x + v.y * bb.y + v.z * bb.z + v.w * bb.w;
        q00 += a.x * a.x + a.y * a.y + a.z * a.z + a.w * a.w;
        q11 += bb.x * bb.x + bb.y * bb.y + bb.z * bb.z + bb.w * bb.w;
    }
    sxx = wave_sum(sxx); sx0 = wave_sum(sx0); sx1 = wave_sum(sx1);
    q00 = wave_sum(q00); q11 = wave_sum(q11);
    if (lane == 0) {
        float invx = 1.0f / fmaxf(sqrtf(sxx), EPS_NORM);
        float iw0  = 1.0f / fmaxf(sqrtf(q00), EPS_NORM);
        float iw1  = 1.0f / fmaxf(sqrtf(q11), EPS_NORM);
        out[((size_t)l * B + b) * 2 + 0] = sx0 * invx * iw0 * TAU_INV;
        out[((size_t)l * B + b) * 2 + 1] = sx1 * invx * iw1 * TAU_INV;
    }
}

// ---------------------------------------------------------------------------
// Kernel 2: seg probabilities — R12 structure + READ-PATH SPLIT experiment.
// Pre-R9: 100% regular loads -> 3.35 TB/s (L3/cached service path).
// R9+:    100% nt loads      -> 5.0  TB/s (HBM-bypass path).
// If the two service paths run concurrently, splitting the stream should add
// their rates: i%3==0 (6/16 = 37.5% of bytes, ~optimal split under
// independence) goes through the cached path (192 MB subset, L3-fits and
// partially persists across replays); the rest via nt.
// ---------------------------------------------------------------------------
__global__ __launch_bounds__(256) void seg_kernel(
        const float* p0, const float* p1, const float* p2, const float* p3,
        const float* what, float* probs) {
    __shared__ float wsm[D];         // this layer's combined weight row (4 KB)

    int bid = blockIdx.x;            // 0..2047
    int l   = bid >> 9;              // 512 blocks per layer
    const float* patch = (l == 0) ? p0 : (l == 1) ? p1 : (l == 2) ? p2 : p3;

    int tid = threadIdx.x;
    // Stage what[l] into LDS once per block.
    *reinterpret_cast<float4*>(wsm + tid * 4) =
        *reinterpret_cast<const float4*>(what + (size_t)l * D + tid * 4);
    __syncthreads();

    int k = tid & 15;                // column group within row
    int r = tid >> 4;                // row within tile (0..15)
    const float* wp = wsm + k * 4;
    int rem0 = (bid & 511) * 64;     // first layer-local row of the 4 tiles

#pragma unroll
    for (int t = 0; t < 4; ++t) {
        int rem = rem0 + t * 16;     // layer-local first row of this tile
        const float* x = patch + (size_t)(rem + r) * D + k * 4;

        float sxx = 0.f, sd = 0.f;
#pragma unroll
        for (int i = 0; i < 16; ++i) {
            f32x4 v;
            if (i % 3 == 0)          // 37.5% via cached path (i=0,3,6,9,12,15)
                v = *reinterpret_cast<const f32x4*>(x + i * 64);
            else                     // 62.5% via nt / HBM-bypass path
                v = __builtin_nontemporal_load(
                        reinterpret_cast<const f32x4*>(x + i * 64));
            const float4 w = *reinterpret_cast<const float4*>(wp + i * 64);
            sxx += v.x * v.x + v.y * v.y + v.z * v.z + v.w * v.w;
            sd  += v.x * w.x + v.y * w.y + v.z * w.z + v.w * w.w;
        }
#pragma unroll
        for (int m = 1; m < 16; m <<= 1) {
            sxx += __shfl_xor(sxx, m);
            sd  += __shfl_xor(sd, m);
        }
        float diff = sd / fmaxf(sqrtf(sxx), EPS_NORM);   // l0 - l1, tau folded in
        float e    = __expf(-diff);
        float pr0  = 1.0f / (1.0f + e);
        float pr1  = pr0 * e;

        int lane = tid & 63;
        float a0 = __shfl(pr0, 0),  a1 = __shfl(pr0, 16);
        float a2 = __shfl(pr0, 32), a3 = __shfl(pr0, 48);
        float b0 = __shfl(pr1, 0),  b1 = __shfl(pr1, 16);
        float b2 = __shfl(pr1, 32), b3 = __shfl(pr1, 48);
        if (lane == 0) {
            int wv  = tid >> 6;                  // wave index in block (0..3)
            int big = rem >> 10;                 // image index
            int n0  = (rem & 1023) + wv * 4;     // first of this wave's 4 rows
            float* o = probs + ((size_t)(l * B + big) * 2) * N;
            *reinterpret_cast<float4*>(o + n0)     = make_float4(a0, a1, a2, a3);
            *reinterpret_cast<float4*>(o + N + n0) = make_float4(b0, b1, b2, b3);
        }
    }
}

// ---------------------------------------------------------------------------
// Kernel 3: bilinear 16x upsample 32x32 -> 512x512 per image. (~22 us
// in-window; writes L3-absorbed.)
// ---------------------------------------------------------------------------
__global__ __launch_bounds__(256) void upsample_kernel(const float* probs, float* out) {
    __shared__ float rowbuf[64 * 32];

    int img   = blockIdx.x >> 3;     // 0..255
    int chunk = blockIdx.x & 7;      // 0..7 (64 output rows each)
    const float* S = probs + (size_t)img * (SIDE * SIDE);

    for (int e = threadIdx.x; e < 64 * 32; e += 256) {
        int r = e >> 5;
        int xs = e & 31;
        int gy = chunk * 64 + r;
        float fy = fmaxf(((float)gy + 0.5f) * 0.0625f - 0.5f, 0.0f);
        int y0 = min((int)fy, SIDE - 1);
        int y1 = min(y0 + 1, SIDE - 1);
        float wy = fy - (float)y0;
        float a = S[y0 * SIDE + xs];
        float b = S[y1 * SIDE + xs];
        rowbuf[e] = a + wy * (b - a);
    }
    __syncthreads();

    int tid = threadIdx.x;
    int xv  = tid & 127;             // float4 column, fixed across iterations
    int rhalf = tid >> 7;            // 0/1
    float fx0 = fmaxf(((float)(4 * xv) + 0.5f) * 0.0625f - 0.5f, 0.0f);
    int x0 = min((int)fx0, SIDE - 1);
    int x1 = min(x0 + 1, SIDE - 1);
    float wx[4];
#pragma unroll
    for (int j = 0; j < 4; ++j) {
        float fx = fmaxf(((float)(4 * xv + j) + 0.5f) * 0.0625f - 0.5f, 0.0f);
        wx[j] = fx - (float)x0;
    }

    float4* obase = reinterpret_cast<float4*>(out) + (size_t)img * (OUT * OUT / 4);
#pragma unroll 8
    for (int it = 0; it < 32; ++it) {
        int r = it * 2 + rhalf;
        const float* rb = rowbuf + r * 32;
        float r0 = rb[x0];
        float d  = rb[x1] - r0;
        float4 o;
        o.x = r0 + wx[0] * d;
        o.y = r0 + wx[1] * d;
        o.z = r0 + wx[2] * d;
        o.w = r0 + wx[3] * d;
        int gy = chunk * 64 + r;
        obase[(size_t)gy * (OUT / 4) + xv] = o;
    }
}

// ---------------------------------------------------------------------------
extern "C" void kernel_launch(void* const* d_in, const int* in_sizes, int n_in,
                              void* d_out, int out_size, void* d_ws, size_t ws_size,
                              hipStream_t stream) {
    const float* cls[4];  const float* patch[4];
    const float* wcls[4]; const float* wseg[4];
    for (int l = 0; l < 4; ++l) {
        cls[l]   = (const float*)d_in[4 * l + 0];
        patch[l] = (const float*)d_in[4 * l + 1];
        wcls[l]  = (const float*)d_in[4 * l + 2];
        wseg[l]  = (const float*)d_in[4 * l + 3];
    }
    float* out = (float*)d_out;            // [4,32,2] cls logits then [4,32,2,512,512]
    float* seg_out = out + NLAYER * B * 2; // offset 256 floats

    float* ws_what  = (float*)d_ws;        // [4][1024] combined weights (16 KB)
    float* ws_probs = ws_what + NLAYER * D;// [4][32][2][1024] = 1 MB

    cls_prep_kernel<<<33, 256, 0, stream>>>(cls[0], wcls[0], cls[1], wcls[1],
                                            cls[2], wcls[2], cls[3], wcls[3],
                                            wseg[0], wseg[1], wseg[2], wseg[3],
                                            out, ws_what);

    seg_kernel<<<2048, 256, 0, stream>>>(patch[0], patch[1], patch[2], patch[3],
                                         ws_what, ws_probs);

    upsample_kernel<<<2048, 256, 0, stream>>>(ws_probs, seg_out);
}

// Round 14
// 132.250 us; speedup vs baseline: 1.3791x; 1.3791x over previous
//
#include <hip/hip_runtime.h>
#include <math.h>

// Problem constants (fixed by setup_inputs)
#define D 1024
#define B 32
#define N 1024          // patches per image (32x32)
#define SIDE 32
#define OUT 512
#define NLAYER 4
#define TAU_INV (1.0f/0.07f)
#define EPS_NORM 1e-12f

typedef float f32x4 __attribute__((ext_vector_type(4)));

__device__ __forceinline__ float wave_sum(float s) {
#pragma unroll
    for (int m = 32; m; m >>= 1) s += __shfl_xor(s, m);
    return s;
}

// ---------------------------------------------------------------------------
// Kernel 1: cls logits (blocks 0..31) + combined seg-weight prep (block 32).
//   what[l][:] = (w0/||w0|| - w1/||w1||) / tau    (seg logit-diff = x.what/||x||)
// ---------------------------------------------------------------------------
__global__ void cls_prep_kernel(const float* c0, const float* wc0,
                                const float* c1, const float* wc1,
                                const float* c2, const float* wc2,
                                const float* c3, const float* wc3,
                                const float* s0, const float* s1,
                                const float* s2, const float* s3,
                                float* out, float* what) {
    if (blockIdx.x == 32) {
        // prep: wave l handles layer l
        int l = threadIdx.x >> 6;
        int lane = threadIdx.x & 63;
        const float* w = (l == 0) ? s0 : (l == 1) ? s1 : (l == 2) ? s2 : s3;
        float4 wa[4], wb[4];
        float q00 = 0.f, q11 = 0.f;
#pragma unroll
        for (int kk = 0; kk < 4; ++kk) {
            int off = kk * 256 + lane * 4;
            wa[kk] = *reinterpret_cast<const float4*>(w + off);
            wb[kk] = *reinterpret_cast<const float4*>(w + D + off);
            q00 += wa[kk].x * wa[kk].x + wa[kk].y * wa[kk].y + wa[kk].z * wa[kk].z + wa[kk].w * wa[kk].w;
            q11 += wb[kk].x * wb[kk].x + wb[kk].y * wb[kk].y + wb[kk].z * wb[kk].z + wb[kk].w * wb[kk].w;
        }
        q00 = wave_sum(q00); q11 = wave_sum(q11);
        float iw0 = TAU_INV / fmaxf(sqrtf(q00), EPS_NORM);
        float iw1 = TAU_INV / fmaxf(sqrtf(q11), EPS_NORM);
        float* o = what + (size_t)l * D;
#pragma unroll
        for (int kk = 0; kk < 4; ++kk) {
            int off = kk * 256 + lane * 4;
            float4 r;
            r.x = wa[kk].x * iw0 - wb[kk].x * iw1;
            r.y = wa[kk].y * iw0 - wb[kk].y * iw1;
            r.z = wa[kk].z * iw0 - wb[kk].z * iw1;
            r.w = wa[kk].w * iw0 - wb[kk].w * iw1;
            *reinterpret_cast<float4*>(o + off) = r;
        }
        return;
    }

    int wid = blockIdx.x * 4 + (threadIdx.x >> 6);   // 0..127
    int lane = threadIdx.x & 63;
    int l = wid >> 5;
    int b = wid & 31;
    const float* cls; const float* wc;
    if      (l == 0) { cls = c0; wc = wc0; }
    else if (l == 1) { cls = c1; wc = wc1; }
    else if (l == 2) { cls = c2; wc = wc2; }
    else             { cls = c3; wc = wc3; }
    const float* x = cls + (size_t)b * D;

    float sxx = 0.f, sx0 = 0.f, sx1 = 0.f, q00 = 0.f, q11 = 0.f;
#pragma unroll
    for (int kk = 0; kk < 4; ++kk) {
        int off = kk * 256 + lane * 4;
        const float4 v  = *reinterpret_cast<const float4*>(x + off);
        const float4 a  = *reinterpret_cast<const float4*>(wc + off);
        const float4 bb = *reinterpret_cast<const float4*>(wc + D + off);
        sxx += v.x * v.x + v.y * v.y + v.z * v.z + v.w * v.w;
        sx0 += v.x * a.x + v.y * a.y + v.z * a.z + v.w * a.w;
        sx1 += v.x * bb.x + v.y * bb.y + v.z * bb.z + v.w * bb.w;
        q00 += a.x * a.x + a.y * a.y + a.z * a.z + a.w * a.w;
        q11 += bb.x * bb.x + bb.y * bb.y + bb.z * bb.z + bb.w * bb.w;
    }
    sxx = wave_sum(sxx); sx0 = wave_sum(sx0); sx1 = wave_sum(sx1);
    q00 = wave_sum(q00); q11 = wave_sum(q11);
    if (lane == 0) {
        float invx = 1.0f / fmaxf(sqrtf(sxx), EPS_NORM);
        float iw0  = 1.0f / fmaxf(sqrtf(q00), EPS_NORM);
        float iw1  = 1.0f / fmaxf(sqrtf(q11), EPS_NORM);
        out[((size_t)l * B + b) * 2 + 0] = sx0 * invx * iw0 * TAU_INV;
        out[((size_t)l * B + b) * 2 + 1] = sx1 * invx * iw1 * TAU_INV;
    }
}

// ---------------------------------------------------------------------------
// Kernel 2: seg probabilities — BEST CONFIG (R12): 100% nt streaming loads +
// 4-tile grid-stride. R13's cached/nt split regressed to 154 us (any cached
// loads reinstate the L3-path bottleneck for the whole stream); reverted.
// 2048 blocks, block b handles tiles b*4..b*4+3 (512 blocks/layer exactly).
// ---------------------------------------------------------------------------
__global__ __launch_bounds__(256) void seg_kernel(
        const float* p0, const float* p1, const float* p2, const float* p3,
        const float* what, float* probs) {
    __shared__ float wsm[D];         // this layer's combined weight row (4 KB)

    int bid = blockIdx.x;            // 0..2047
    int l   = bid >> 9;              // 512 blocks per layer
    const float* patch = (l == 0) ? p0 : (l == 1) ? p1 : (l == 2) ? p2 : p3;

    int tid = threadIdx.x;
    // Stage what[l] into LDS once per block.
    *reinterpret_cast<float4*>(wsm + tid * 4) =
        *reinterpret_cast<const float4*>(what + (size_t)l * D + tid * 4);
    __syncthreads();

    int k = tid & 15;                // column group within row
    int r = tid >> 4;                // row within tile (0..15)
    const float* wp = wsm + k * 4;
    int rem0 = (bid & 511) * 64;     // first layer-local row of the 4 tiles

#pragma unroll
    for (int t = 0; t < 4; ++t) {
        int rem = rem0 + t * 16;     // layer-local first row of this tile
        const float* x = patch + (size_t)(rem + r) * D + k * 4;

        float sxx = 0.f, sd = 0.f;
#pragma unroll
        for (int i = 0; i < 16; ++i) {
            const f32x4 v = __builtin_nontemporal_load(
                reinterpret_cast<const f32x4*>(x + i * 64));
            const float4 w = *reinterpret_cast<const float4*>(wp + i * 64);
            sxx += v.x * v.x + v.y * v.y + v.z * v.z + v.w * v.w;
            sd  += v.x * w.x + v.y * w.y + v.z * w.z + v.w * w.w;
        }
#pragma unroll
        for (int m = 1; m < 16; m <<= 1) {
            sxx += __shfl_xor(sxx, m);
            sd  += __shfl_xor(sd, m);
        }
        float diff = sd / fmaxf(sqrtf(sxx), EPS_NORM);   // l0 - l1, tau folded in
        float e    = __expf(-diff);
        float pr0  = 1.0f / (1.0f + e);
        float pr1  = pr0 * e;

        int lane = tid & 63;
        float a0 = __shfl(pr0, 0),  a1 = __shfl(pr0, 16);
        float a2 = __shfl(pr0, 32), a3 = __shfl(pr0, 48);
        float b0 = __shfl(pr1, 0),  b1 = __shfl(pr1, 16);
        float b2 = __shfl(pr1, 32), b3 = __shfl(pr1, 48);
        if (lane == 0) {
            int wv  = tid >> 6;                  // wave index in block (0..3)
            int big = rem >> 10;                 // image index
            int n0  = (rem & 1023) + wv * 4;     // first of this wave's 4 rows
            float* o = probs + ((size_t)(l * B + big) * 2) * N;
            *reinterpret_cast<float4*>(o + n0)     = make_float4(a0, a1, a2, a3);
            *reinterpret_cast<float4*>(o + N + n0) = make_float4(b0, b1, b2, b3);
        }
    }
}

// ---------------------------------------------------------------------------
// Kernel 3: bilinear 16x upsample 32x32 -> 512x512 per image. (~22 us
// in-window; writes L3-absorbed.)
// ---------------------------------------------------------------------------
__global__ __launch_bounds__(256) void upsample_kernel(const float* probs, float* out) {
    __shared__ float rowbuf[64 * 32];

    int img   = blockIdx.x >> 3;     // 0..255
    int chunk = blockIdx.x & 7;      // 0..7 (64 output rows each)
    const float* S = probs + (size_t)img * (SIDE * SIDE);

    for (int e = threadIdx.x; e < 64 * 32; e += 256) {
        int r = e >> 5;
        int xs = e & 31;
        int gy = chunk * 64 + r;
        float fy = fmaxf(((float)gy + 0.5f) * 0.0625f - 0.5f, 0.0f);
        int y0 = min((int)fy, SIDE - 1);
        int y1 = min(y0 + 1, SIDE - 1);
        float wy = fy - (float)y0;
        float a = S[y0 * SIDE + xs];
        float b = S[y1 * SIDE + xs];
        rowbuf[e] = a + wy * (b - a);
    }
    __syncthreads();

    int tid = threadIdx.x;
    int xv  = tid & 127;             // float4 column, fixed across iterations
    int rhalf = tid >> 7;            // 0/1
    float fx0 = fmaxf(((float)(4 * xv) + 0.5f) * 0.0625f - 0.5f, 0.0f);
    int x0 = min((int)fx0, SIDE - 1);
    int x1 = min(x0 + 1, SIDE - 1);
    float wx[4];
#pragma unroll
    for (int j = 0; j < 4; ++j) {
        float fx = fmaxf(((float)(4 * xv + j) + 0.5f) * 0.0625f - 0.5f, 0.0f);
        wx[j] = fx - (float)x0;
    }

    float4* obase = reinterpret_cast<float4*>(out) + (size_t)img * (OUT * OUT / 4);
#pragma unroll 8
    for (int it = 0; it < 32; ++it) {
        int r = it * 2 + rhalf;
        const float* rb = rowbuf + r * 32;
        float r0 = rb[x0];
        float d  = rb[x1] - r0;
        float4 o;
        o.x = r0 + wx[0] * d;
        o.y = r0 + wx[1] * d;
        o.z = r0 + wx[2] * d;
        o.w = r0 + wx[3] * d;
        int gy = chunk * 64 + r;
        obase[(size_t)gy * (OUT / 4) + xv] = o;
    }
}

// ---------------------------------------------------------------------------
extern "C" void kernel_launch(void* const* d_in, const int* in_sizes, int n_in,
                              void* d_out, int out_size, void* d_ws, size_t ws_size,
                              hipStream_t stream) {
    const float* cls[4];  const float* patch[4];
    const float* wcls[4]; const float* wseg[4];
    for (int l = 0; l < 4; ++l) {
        cls[l]   = (const float*)d_in[4 * l + 0];
        patch[l] = (const float*)d_in[4 * l + 1];
        wcls[l]  = (const float*)d_in[4 * l + 2];
        wseg[l]  = (const float*)d_in[4 * l + 3];
    }
    float* out = (float*)d_out;            // [4,32,2] cls logits then [4,32,2,512,512]
    float* seg_out = out + NLAYER * B * 2; // offset 256 floats

    float* ws_what  = (float*)d_ws;        // [4][1024] combined weights (16 KB)
    float* ws_probs = ws_what + NLAYER * D;// [4][32][2][1024] = 1 MB

    cls_prep_kernel<<<33, 256, 0, stream>>>(cls[0], wcls[0], cls[1], wcls[1],
                                            cls[2], wcls[2], cls[3], wcls[3],
                                            wseg[0], wseg[1], wseg[2], wseg[3],
                                            out, ws_what);

    seg_kernel<<<2048, 256, 0, stream>>>(patch[0], patch[1], patch[2], patch[3],
                                         ws_what, ws_probs);

    upsample_kernel<<<2048, 256, 0, stream>>>(ws_probs, seg_out);
}